// Round 1
// baseline (339.915 us; speedup 1.0000x reference)
//
#include <hip/hip_runtime.h>
#include <math.h>

#define HDIM 2048
#define WDIM 2048
#define NIMG 4
#define NPIX (HDIM*WDIM)
#define OUTW 2038          /* valid conv output size: 2048-10 */

#define C1F 6.5025f        /* (0.01*255)^2 */
#define C2F 58.5225f       /* (0.03*255)^2 */

// Quantization exactly mirroring the reference _to_uint8_float op sequence (f32).
__device__ __forceinline__ float quant_u8(float x) {
    float xc  = fminf(fmaxf(x, -1.0f), 1.0f);
    float x01 = (xc + 1.0f) * 0.5f;
    x01 = fminf(fmaxf(x01, 0.0f), 1.0f);
    float v = x01 * 255.0f;
    v = fminf(fmaxf(v, 0.0f), 255.0f);
    return floorf(v);
}

// ---------------------------------------------------------------------------
// Kernel 1: streaming reductions.
// Grid: 1024 blocks x 256 thr; blocks [b*256,(b+1)*256) own image b.
// Partial layout (floats): pr[c*1024 + blockIdx.x], counters:
//   0 sum|p-t|  1 sum|d_gx|  2 sum|d_gy|  3 sum relu(|p|-1)
//   4 sum p     5 sum t      6 sum p^2    7 sum t^2   8 sum (p8-t8)^2
// ---------------------------------------------------------------------------
__global__ __launch_bounds__(256) void amsr2_reduce(
        const float* __restrict__ pred, const float* __restrict__ targ,
        float* __restrict__ pr)
{
    const int blk = blockIdx.x;
    const int b   = blk >> 8;
    const int cb  = blk & 255;
    const float* p = pred + (size_t)b * NPIX;
    const float* t = targ + (size_t)b * NPIX;

    float s[9];
#pragma unroll
    for (int c = 0; c < 9; ++c) s[c] = 0.0f;

    const int groups = NPIX / 4;         // 4 pixels per thread-iteration
    const int stride = 256 * 256;        // threads per image
    for (int gix = cb * 256 + threadIdx.x; gix < groups; gix += stride) {
        int i = gix * 4;
        int h = i >> 11;
        int w = i & 2047;
        float4 p4 = *(const float4*)(p + i);
        float4 t4 = *(const float4*)(t + i);
        bool down = (h < HDIM - 1);
        float4 pd4 = down ? *(const float4*)(p + i + WDIM) : make_float4(0.f,0.f,0.f,0.f);
        float4 td4 = down ? *(const float4*)(t + i + WDIM) : make_float4(0.f,0.f,0.f,0.f);
        bool r4 = (w + 4 < WDIM);
        float p5 = r4 ? p[i + 4] : 0.0f;
        float t5 = r4 ? t[i + 4] : 0.0f;
        float pv[5] = {p4.x, p4.y, p4.z, p4.w, p5};
        float tv[5] = {t4.x, t4.y, t4.z, t4.w, t5};
        float pd[4] = {pd4.x, pd4.y, pd4.z, pd4.w};
        float td[4] = {td4.x, td4.y, td4.z, td4.w};
#pragma unroll
        for (int k = 0; k < 4; ++k) {
            float av = pv[k], bv = tv[k];
            float d = av - bv;
            s[0] += fabsf(d);
            s[3] += fmaxf(fabsf(av) - 1.0f, 0.0f);
            s[4] += av;  s[5] += bv;
            s[6] += av * av;  s[7] += bv * bv;
            float q = quant_u8(av) - quant_u8(bv);
            s[8] += q * q;
            if (down) {                         // gradient along H
                float dd = pd[k] - td[k];
                s[1] += fabsf(d - dd);
            }
            if (w + k < WDIM - 1) {             // gradient along W
                float dr = pv[k+1] - tv[k+1];
                s[2] += fabsf(d - dr);
            }
        }
    }

    __shared__ float red[4][9];
#pragma unroll
    for (int c = 0; c < 9; ++c) {
        float v = s[c];
        for (int off = 32; off > 0; off >>= 1) v += __shfl_down(v, off);
        s[c] = v;
    }
    int lane = threadIdx.x & 63, wid = threadIdx.x >> 6;
    if (lane == 0) {
#pragma unroll
        for (int c = 0; c < 9; ++c) red[wid][c] = s[c];
    }
    __syncthreads();
    if (threadIdx.x < 9) {
        int c = threadIdx.x;
        pr[c * 1024 + blk] = red[0][c] + red[1][c] + red[2][c] + red[3][c];
    }
}

// ---------------------------------------------------------------------------
// Kernel 2: tiled separable SSIM. Tile = 64 rows x 32 cols of output.
// LDS: quantized inputs packed u8x4 (74 rows x 48B, 2 arrays = 7.1 KB) +
//      5 horizontal-conv arrays (74 x 32 f32 = 47.3 KB). Total 54.4 KB.
// ---------------------------------------------------------------------------
constexpr int TH  = 64, TW = 32;
constexpr int IH  = TH + 10;   // 74 input rows
constexpr int IWD = 12;        // dwords per LDS input row (48 B; cols 0..41 used)
constexpr int HS  = 32;        // h-array row stride (floats)

__global__ __launch_bounds__(256) void amsr2_ssim(
        const float* __restrict__ pred, const float* __restrict__ targ,
        float* __restrict__ spart)
{
    __shared__ unsigned sp[IH * IWD];
    __shared__ unsigned st[IH * IWD];
    __shared__ alignas(16) float hp [IH*HS];
    __shared__ alignas(16) float ht [IH*HS];
    __shared__ alignas(16) float hpp[IH*HS];
    __shared__ alignas(16) float htt[IH*HS];
    __shared__ alignas(16) float hpt[IH*HS];

    // Gaussian weights in f64 (matches numpy), cast to f32.
    float g[11];
    {
        double e[11], sm = 0.0;
#pragma unroll
        for (int i = 0; i < 11; ++i) { double d = (double)(i - 5); e[i] = exp(-(d*d)/4.5); sm += e[i]; }
#pragma unroll
        for (int i = 0; i < 11; ++i) g[i] = (float)(e[i] / sm);
    }

    const int b  = blockIdx.z;
    const int r0 = blockIdx.y * TH;
    const int c0 = blockIdx.x * TW;
    const float* p = pred + (size_t)b * NPIX;
    const float* t = targ + (size_t)b * NPIX;

    // ---- stage A: load, quantize, pack u8x4 into LDS ----
    for (int item = threadIdx.x; item < IH * IWD; item += 256) {
        int r = item / IWD, d = item - r * IWD;
        int gr = r0 + r;
        int gc0 = c0 + d * 4;
        unsigned up = 0u, ut = 0u;
        if (gr < HDIM) {
            const float* prow = p + (size_t)gr * WDIM;
            const float* trow = t + (size_t)gr * WDIM;
#pragma unroll
            for (int k = 0; k < 4; ++k) {
                int cc = d * 4 + k;
                int gc = gc0 + k;
                if (cc < 42 && gc < WDIM) {
                    up |= ((unsigned)(int)quant_u8(prow[gc])) << (8*k);
                    ut |= ((unsigned)(int)quant_u8(trow[gc])) << (8*k);
                }
            }
        }
        sp[item] = up; st[item] = ut;
    }
    __syncthreads();

    // ---- stage B: horizontal 11-tap conv of {p,t,p^2,t^2,pt}, 4 outputs/item ----
    for (int item = threadIdx.x; item < IH * 8; item += 256) {
        int r = item >> 3, c4 = item & 7;
        int base = r * IWD + c4;
        float pv[16], tv[16];
#pragma unroll
        for (int q = 0; q < 4; ++q) {
            unsigned ua = sp[base + q], ub = st[base + q];
#pragma unroll
            for (int k = 0; k < 4; ++k) {
                pv[q*4+k] = (float)((ua >> (8*k)) & 0xffu);
                tv[q*4+k] = (float)((ub >> (8*k)) & 0xffu);
            }
        }
        float spv[4]  = {0,0,0,0}, stv[4]  = {0,0,0,0};
        float sppv[4] = {0,0,0,0}, sttv[4] = {0,0,0,0}, sptv[4] = {0,0,0,0};
#pragma unroll
        for (int j = 0; j < 11; ++j) {
            float gj = g[j];
#pragma unroll
            for (int o = 0; o < 4; ++o) {
                float a = pv[o + j], c = tv[o + j];
                spv[o]  += gj * a;
                stv[o]  += gj * c;
                sppv[o] += gj * (a * a);
                sttv[o] += gj * (c * c);
                sptv[o] += gj * (a * c);
            }
        }
        int hb = r * HS + c4 * 4;
        *(float4*)(hp  + hb) = make_float4(spv[0],  spv[1],  spv[2],  spv[3]);
        *(float4*)(ht  + hb) = make_float4(stv[0],  stv[1],  stv[2],  stv[3]);
        *(float4*)(hpp + hb) = make_float4(sppv[0], sppv[1], sppv[2], sppv[3]);
        *(float4*)(htt + hb) = make_float4(sttv[0], sttv[1], sttv[2], sttv[3]);
        *(float4*)(hpt + hb) = make_float4(sptv[0], sptv[1], sptv[2], sptv[3]);
    }
    __syncthreads();

    // ---- stage C: vertical 11-tap + SSIM map; 2 rows x 4 cols per thread ----
    const int th_ = min(TH, OUTW - r0);
    const int tw_ = min(TW, OUTW - c0);
    float ssum = 0.0f;
    {
        int oy0 = (threadIdx.x >> 3) * 2;
        int ox0 = (threadIdx.x & 7) * 4;
        float acc[2][5][4];
#pragma unroll
        for (int r = 0; r < 2; ++r)
#pragma unroll
            for (int a = 0; a < 5; ++a)
#pragma unroll
                for (int c = 0; c < 4; ++c) acc[r][a][c] = 0.0f;
#pragma unroll
        for (int j = 0; j < 12; ++j) {
            int hb = (oy0 + j) * HS + ox0;
            float4 q0 = *(const float4*)(hp  + hb);
            float4 q1 = *(const float4*)(ht  + hb);
            float4 q2 = *(const float4*)(hpp + hb);
            float4 q3 = *(const float4*)(htt + hb);
            float4 q4 = *(const float4*)(hpt + hb);
            float qs[5][4] = {
                {q0.x,q0.y,q0.z,q0.w},{q1.x,q1.y,q1.z,q1.w},{q2.x,q2.y,q2.z,q2.w},
                {q3.x,q3.y,q3.z,q3.w},{q4.x,q4.y,q4.z,q4.w}};
            if (j < 11) {
                float gj = g[j];
#pragma unroll
                for (int a = 0; a < 5; ++a)
#pragma unroll
                    for (int c = 0; c < 4; ++c) acc[0][a][c] += gj * qs[a][c];
            }
            if (j >= 1) {
                float gj = g[j-1];
#pragma unroll
                for (int a = 0; a < 5; ++a)
#pragma unroll
                    for (int c = 0; c < 4; ++c) acc[1][a][c] += gj * qs[a][c];
            }
        }
#pragma unroll
        for (int r = 0; r < 2; ++r) {
            if (oy0 + r < th_) {
#pragma unroll
                for (int c = 0; c < 4; ++c) {
                    if (ox0 + c < tw_) {
                        float mu1 = acc[r][0][c], mu2 = acc[r][1][c];
                        float vpp = acc[r][2][c], vtt = acc[r][3][c], vpt = acc[r][4][c];
                        float mu1s = mu1*mu1, mu2s = mu2*mu2, mu12 = mu1*mu2;
                        float sg1 = vpp - mu1s, sg2 = vtt - mu2s, sg12 = vpt - mu12;
                        float num = (2.0f*mu12 + C1F) * (2.0f*sg12 + C2F);
                        float den = (mu1s + mu2s + C1F) * (sg1 + sg2 + C2F);
                        ssum += num / den;
                    }
                }
            }
        }
    }
    float v = ssum;
    for (int off = 32; off > 0; off >>= 1) v += __shfl_down(v, off);
    __shared__ float sred[4];
    int lane = threadIdx.x & 63, wid = threadIdx.x >> 6;
    if (lane == 0) sred[wid] = v;
    __syncthreads();
    if (threadIdx.x == 0) {
        int bid = (blockIdx.z * gridDim.y + blockIdx.y) * gridDim.x + blockIdx.x;
        spart[bid] = sred[0] + sred[1] + sred[2] + sred[3];
    }
}

// ---------------------------------------------------------------------------
// Kernel 3: combine partials (f64) -> (total, psnr_mean, ssim_mean).
// 28 segments reduced wave-parallel (no serialized block_sum chain).
// ---------------------------------------------------------------------------
__global__ __launch_bounds__(256) void amsr2_final(
        const float* __restrict__ pr, const float* __restrict__ spart,
        float* __restrict__ out)
{
    __shared__ double res[28];
    int wid = threadIdx.x >> 6, lane = threadIdx.x & 63;
    for (int c = wid; c < 28; c += 4) {
        const float* base; int n;
        if (c < 4)       { base = pr + c * 1024; n = 1024; }
        else if (c < 24) { int cc = c - 4; int ctr = cc >> 2; int bb = cc & 3;
                           base = pr + (4 + ctr) * 1024 + bb * 256; n = 256; }
        else             { int bb = c - 24; base = spart + bb * 2048; n = 2048; }
        double sacc = 0.0;
        for (int i = lane; i < n; i += 64) sacc += (double)base[i];
        for (int off = 32; off > 0; off >>= 1) sacc += __shfl_down(sacc, off);
        if (lane == 0) res[c] = sacc;
    }
    __syncthreads();
    if (threadIdx.x == 0) {
        const double n = (double)NPIX;
        double l1   = res[0] / (4.0 * n);
        double grad = res[1] / (4.0 * 2047.0 * 2048.0) + res[2] / (4.0 * 2048.0 * 2047.0);
        double energy = 0.0, dist = 0.0, psnr_sum = 0.0, ssim_sum = 0.0;
        for (int b = 0; b < 4; ++b) {
            double Sp  = res[4 + b],  St  = res[8 + b];
            double Spp = res[12 + b], Stt = res[16 + b];
            double Su8 = res[20 + b], Sss = res[24 + b];
            double pm = Sp / n, tm = St / n;
            double dm = pm - tm; energy += dm * dm;
            double vp = (Spp - n * pm * pm) / (n - 1.0);
            double vt = (Stt - n * tm * tm) / (n - 1.0);
            double ps = sqrt(fmax(vp, 0.0)), ts = sqrt(fmax(vt, 0.0));
            double dd = ps - ts; dist += dd * dd;
            double mse = Su8 / n;
            double psnr = (mse == 0.0) ? 100.0 : 10.0 * log10(65025.0 / fmax(mse, 1e-12));
            psnr_sum += psnr;
            ssim_sum += Sss / ((double)OUTW * (double)OUTW);
        }
        energy *= 0.25; dist *= 0.25;
        double range_pen = res[3] / (4.0 * n);
        double phys = energy + 0.5 * dist + 0.1 * range_pen;
        double ssim_mean = fmin(fmax(ssim_sum * 0.25, 0.0), 1.0);
        double total = l1 + 0.15 * grad + 0.05 * phys + 0.1 * (1.0 - ssim_mean);
        out[0] = (float)total;
        out[1] = (float)(psnr_sum * 0.25);
        out[2] = (float)ssim_mean;
    }
}

extern "C" void kernel_launch(void* const* d_in, const int* in_sizes, int n_in,
                              void* d_out, int out_size, void* d_ws, size_t ws_size,
                              hipStream_t stream)
{
    (void)in_sizes; (void)n_in; (void)out_size; (void)ws_size;
    const float* pred = (const float*)d_in[0];
    const float* targ = (const float*)d_in[1];
    float* out   = (float*)d_out;
    float* pr    = (float*)d_ws;           // 9*1024 floats of reduce partials
    float* spart = pr + 9 * 1024;          // 8192 floats of ssim partials
    amsr2_reduce<<<1024, 256, 0, stream>>>(pred, targ, pr);
    amsr2_ssim<<<dim3(64, 32, 4), 256, 0, stream>>>(pred, targ, spart);
    amsr2_final<<<1, 256, 0, stream>>>(pr, spart, out);
}